// Round 12
// baseline (568.877 us; speedup 1.0000x reference)
//
#include <hip/hip_runtime.h>
#include <hip/hip_cooperative_groups.h>
#include <math.h>
#include <string.h>

namespace cg = cooperative_groups;

#define T_SEQ 4096
#define DM 1024
#define NH 16
#define HD 64

typedef short s8v __attribute__((ext_vector_type(8)));
typedef float f4v __attribute__((ext_vector_type(4)));

__device__ inline unsigned short f2bf(float f) {
    unsigned u; memcpy(&u, &f, 4);
    u = u + 0x7fffu + ((u >> 16) & 1u);   // RNE
    return (unsigned short)(u >> 16);
}

__device__ inline float bf2f(unsigned short s) {
    unsigned u = (unsigned)s << 16;
    float f; memcpy(&f, &u, 4);
    return f;
}

__device__ inline float exp2fn(float x) {
#if __has_builtin(__builtin_amdgcn_exp2f)
    return __builtin_amdgcn_exp2f(x);
#else
    return exp2f(x);
#endif
}

__device__ inline void gld_lds16(const void* g, void* l) {
    __builtin_amdgcn_global_load_lds(
        (const __attribute__((address_space(1))) void*)g,
        (__attribute__((address_space(3))) void*)l, 16, 0, 0);
}

// ---------------- stage bodies (r7/r11-proven logic) ----------------

// bf16 MFMA GEMM, fat tiles, double-buffered LDS, XCD-patch swizzle.
// MODE 2: qkv-special (Q/K row-major bf16, V sigma fragment-image).
// MODE 0: fp32 row-major out + bias.
template<int MODE, int TM, int TN, int WR, int WC>
__device__ void gemm_body(char* smem_,
                          const unsigned short* __restrict__ A, const unsigned short* __restrict__ B,
                          const float* __restrict__ bias, void* __restrict__ Cout,
                          unsigned short* __restrict__ qbuf, unsigned short* __restrict__ kbuf2,
                          unsigned short* __restrict__ vT,
                          int M, int N, int K, int nbx, int patchw, int patchh) {
    constexpr int W  = WR * WC;
    constexpr int MF = TM / WR / 16;
    constexpr int NF = TN / WC / 16;
    constexpr int NGA = TM / 16, NGB = TN / 16, NG = NGA + NGB;
    short* AsB = (short*)smem_;                     // 2 bufs x TM*32 shorts
    short* BsB = (short*)smem_ + 2 * TM * 32;       // 2 bufs x TN*32 shorts
    const int tid = threadIdx.x;
    const int w = tid >> 6, lane = tid & 63;
    const int wr = w / WC, wc = w % WC;
    const int l15 = lane & 15, quad = lane >> 4;

    // XCD-patch block swizzle (bijective: grid = 8 * patchw * patchh)
    const int bl = blockIdx.x;
    const int xcd = bl & 7, ii = bl >> 3;
    const int pxn = nbx / patchw;
    const int bx = (xcd % pxn) * patchw + ii % patchw;
    const int by = (xcd / pxn) * patchh + ii / patchw;
    const int m0 = by * TM, n0 = bx * TN;

    f4v acc[MF][NF];
    #pragma unroll
    for (int i = 0; i < MF; ++i)
        #pragma unroll
        for (int j = 0; j < NF; ++j) acc[i][j] = (f4v){0.f, 0.f, 0.f, 0.f};

    auto stage = [&](int buf, int k0) {
        short* As = AsB + buf * TM * 32;
        short* Bs = BsB + buf * TN * 32;
        for (int g = w; g < NG; g += W) {
            if (g < NGA)
                gld_lds16(A + (size_t)(m0 + g * 16 + l15) * K + quad * 8 + k0, &As[g * 512]);
            else
                gld_lds16(B + (size_t)(n0 + (g - NGA) * 16 + l15) * K + quad * 8 + k0,
                          &Bs[(g - NGA) * 512]);
        }
    };
    auto compute = [&](int buf) {
        short* As = AsB + buf * TM * 32;
        short* Bs = BsB + buf * TN * 32;
        s8v af[MF], bfr[NF];
        #pragma unroll
        for (int i = 0; i < MF; ++i)
            af[i] = *(const s8v*)&As[((wr * MF + i) * 64 + lane) * 8];
        #pragma unroll
        for (int j = 0; j < NF; ++j)
            bfr[j] = *(const s8v*)&Bs[((wc * NF + j) * 64 + lane) * 8];
        #pragma unroll
        for (int i = 0; i < MF; ++i)
            #pragma unroll
            for (int j = 0; j < NF; ++j)
                acc[i][j] = __builtin_amdgcn_mfma_f32_16x16x32_bf16(af[i], bfr[j], acc[i][j], 0, 0, 0);
    };

    stage(0, 0);
    __syncthreads();
    for (int k0 = 0; k0 < K; k0 += 64) {
        stage(1, k0 + 32);                 // in flight under compute(0)
        compute(0);
        __syncthreads();
        if (k0 + 64 < K) stage(0, k0 + 64);
        compute(1);
        __syncthreads();
    }

    float bj[NF];
    #pragma unroll
    for (int j = 0; j < NF; ++j) bj[j] = bias[n0 + wc * (TN / WC) + j * 16 + l15];

    if (MODE == 2) {
        #pragma unroll
        for (int j = 0; j < NF; ++j) {
            const int ccol = n0 + wc * (TN / WC) + j * 16;   // wave-uniform, 16-aligned
            if (ccol >= 2 * DM) {
                // V -> sigma fragment-image (r7-proven): d = (ccol&63)+l15,
                // key = tile*64 + it*16 + quad*4 + rg, tile = (m0+wr*(TM/WR))/64+(i>>2)
                const int hh = (ccol - 2 * DM) >> 6;
                const int ob = (ccol & 63) >> 4;
                #pragma unroll
                for (int i = 0; i < MF; ++i) {
                    const int tile = (m0 + wr * (TM / WR)) / 64 + (i >> 2);
                    const int it = i & 3;
                    unsigned short o[4];
                    #pragma unroll
                    for (int rg = 0; rg < 4; ++rg) o[rg] = f2bf(acc[i][j][rg] + bj[j]);
                    unsigned long long pk; memcpy(&pk, o, 8);
                    size_t off = (size_t)hh * 262144 + (size_t)tile * 4096
                               + (size_t)((ob * 2 + (it >> 1)) * 64 + lane) * 8 + (it & 1) * 4;
                    *(unsigned long long*)&vT[off] = pk;
                }
            } else {
                unsigned short* dst = (ccol < DM) ? qbuf : kbuf2;
                const int col = (ccol < DM) ? (ccol + l15) : (ccol - DM + l15);
                #pragma unroll
                for (int i = 0; i < MF; ++i) {
                    #pragma unroll
                    for (int rg = 0; rg < 4; ++rg) {
                        int row = m0 + wr * (TM / WR) + i * 16 + quad * 4 + rg;
                        dst[(size_t)row * DM + col] = f2bf(acc[i][j][rg] + bj[j]);
                    }
                }
            }
        }
    } else {
        #pragma unroll
        for (int i = 0; i < MF; ++i) {
            #pragma unroll
            for (int rg = 0; rg < 4; ++rg) {
                int row = m0 + wr * (TM / WR) + i * 16 + quad * 4 + rg;
                #pragma unroll
                for (int j = 0; j < NF; ++j) {
                    int col = n0 + wc * (TN / WC) + j * 16 + l15;
                    ((float*)Cout)[(size_t)row * N + col] = acc[i][j][rg] + bj[j];
                }
            }
        }
    }
}

// ---- static-max softmax step -> P fragments DIRECT IN REGISTERS ----
__device__ __forceinline__ void soft_step(f4v* st, bool diag, int qloc, int quad,
                                          float& lr, s8v& pf0, s8v& pf1) {
    const float C2  = 0.1803368851f;          // 0.125 * log2(e)
    const float MC2 = 12.0f * 0.1803368851f;  // fixed shift M=12
    float sv[4][4];
    #pragma unroll
    for (int kb = 0; kb < 4; ++kb)
        #pragma unroll
        for (int rg = 0; rg < 4; ++rg) {
            float s = st[kb][rg];
            if (diag && (kb * 16 + quad * 4 + rg > qloc)) s = -3.0e38f;
            float t = exp2fn(fmaf(s, C2, -MC2));
            sv[kb][rg] = t;
            lr += t;
        }
    int pk[4][2];
    #pragma unroll
    for (int kb = 0; kb < 4; ++kb) {
        unsigned u0 = __float_as_uint(sv[kb][0]) + 0x8000u;
        unsigned u1 = __float_as_uint(sv[kb][1]) + 0x8000u;
        unsigned u2 = __float_as_uint(sv[kb][2]) + 0x8000u;
        unsigned u3 = __float_as_uint(sv[kb][3]) + 0x8000u;
        pk[kb][0] = (int)__builtin_amdgcn_perm(u1, u0, 0x07060302);  // bf16(sv0)|bf16(sv1)<<16
        pk[kb][1] = (int)__builtin_amdgcn_perm(u3, u2, 0x07060302);
    }
    int4 a = {pk[0][0], pk[0][1], pk[1][0], pk[1][1]};
    int4 b = {pk[2][0], pk[2][1], pk[3][0], pk[3][1]};
    memcpy(&pf0, &a, 16);
    memcpy(&pf1, &b, 16);
}

// ---- MFMA flash attention, NO k-split (r11 512-thr structure, par removed):
// block (h, a) does q-tiles a and 31-a with ALL k-tiles 0..2qt+1 ->
// lr is the full denominator -> normalized bf16 output written directly
// (combine kernel + partial round-trip eliminated). Work per block =
// (2a+2)+(2(31-a)+2) = 68 tile-steps: exactly balanced. Block map
// b = a*16 + h keeps b%8 = h%8 (2 heads per XCD class, ~2 MB K/V per XCD --
// the round-1 locality invariant). Causal logic r11-verified:
//   lo waves (rows 0..63):  diag at kt==2qt,   skip kt==2qt+1
//   hi waves (rows 64..127): diag at kt==2qt+1, never skip
__device__ void attn_body(char* smem_,
                          const unsigned short* __restrict__ qb,
                          const unsigned short* __restrict__ kbf,
                          const unsigned short* __restrict__ vT,
                          unsigned short* __restrict__ yout) {
    short (*KB)[4096]  = (short(*)[4096])smem_;              // 16 KB
    short (*VTs)[4096] = (short(*)[4096])(smem_ + 16384);    // 16 KB
    short* QB          = (short*)(smem_ + 32768);            // 16 KB
    const int b = blockIdx.x;
    const int h = b & 15, a = b >> 4;       // a in 0..15
    const int tid = threadIdx.x;
    const int w = tid >> 6, lane = tid & 63;
    const int quad = lane >> 4, l15 = lane & 15;
    const int cq = h * HD;
    const unsigned short* vbase = vT + (size_t)h * 262144;   // per-head V image
    const bool lo = (w < 4);
    const int qloc = (w & 3) * 16 + l15;

    for (int ph = 0; ph < 2; ++ph) {
        const int qt = ph ? (31 - a) : a;
        const int q0 = qt * 128;
        const int nk = 2 * qt + 2;          // all tiles 0..2qt+1

        __syncthreads();   // previous phase LDS fully consumed
        // ---- stage Q (16 KB = 1024 chunks, 2 rounds of 512) ----
        #pragma unroll
        for (int rr = 0; rr < 2; ++rr) {
            int ch = rr * 512 + tid;
            int qg = ch >> 7, hf = (ch >> 6) & 1, ln = ch & 63;
            gld_lds16(qb + (size_t)(q0 + qg * 16 + (ln & 15)) * DM + cq + hf * 32 + ((ln >> 4) << 3),
                      &QB[(ch & ~63) * 8]);
        }
        // ---- stage first K/V tile (512 chunks, 1 round) ----
        {
            int ch = tid;
            int blk = ch >> 7, hf = (ch >> 6) & 1, ln = ch & 63;
            gld_lds16(kbf + (size_t)(blk * 16 + (ln & 15)) * DM + cq + hf * 32 + ((ln >> 4) << 3),
                      &KB[0][(ch & ~63) * 8]);
            gld_lds16(vbase + (size_t)ch * 8, &VTs[0][(ch & ~63) * 8]);
        }
        __syncthreads();

        s8v qf[2];
        #pragma unroll
        for (int hf = 0; hf < 2; ++hf)
            qf[hf] = *(const s8v*)&QB[(((w * 2 + hf) * 64) + lane) * 8];

        f4v O[4];
        #pragma unroll
        for (int ob = 0; ob < 4; ++ob) O[ob] = (f4v){0.f, 0.f, 0.f, 0.f};
        float lr = 0.f;

        for (int i = 0; i < nk; ++i) {
            const int kt = i;
            const int p = i & 1;
            const bool diag = lo ? (kt == 2 * qt) : (kt == 2 * qt + 1);
            const bool skip = lo && (kt == 2 * qt + 1);
            if (i < nk - 1) {                      // prefetch next tile (64 keys)
                const int k1 = (i + 1) * 64;
                int ch = tid;
                int blk = ch >> 7, hf = (ch >> 6) & 1, ln = ch & 63;
                gld_lds16(kbf + (size_t)(k1 + blk * 16 + (ln & 15)) * DM + cq
                              + hf * 32 + ((ln >> 4) << 3),
                          &KB[p ^ 1][(ch & ~63) * 8]);
                gld_lds16(vbase + (size_t)(k1 >> 6) * 4096 + (size_t)ch * 8,
                          &VTs[p ^ 1][(ch & ~63) * 8]);
            }

            if (!skip) {
                // ---- S^T for this wave's 16 q-rows ----
                f4v st[4];
                #pragma unroll
                for (int kb = 0; kb < 4; ++kb) {
                    s8v k0f = *(const s8v*)&KB[p][((kb * 2 + 0) * 64 + lane) * 8];
                    s8v k1f = *(const s8v*)&KB[p][((kb * 2 + 1) * 64 + lane) * 8];
                    f4v c = (f4v){0.f, 0.f, 0.f, 0.f};
                    c = __builtin_amdgcn_mfma_f32_16x16x32_bf16(k0f, qf[0], c, 0, 0, 0);
                    c = __builtin_amdgcn_mfma_f32_16x16x32_bf16(k1f, qf[1], c, 0, 0, 0);
                    st[kb] = c;
                }
                // ---- softmax + P fragments in registers ----
                s8v pf0, pf1;
                soft_step(st, diag, qloc, quad, lr, pf0, pf1);
                // ---- O^T += V^T P^T ----
                #pragma unroll
                for (int ob = 0; ob < 4; ++ob) {
                    s8v v0f = *(const s8v*)&VTs[p][((ob * 2 + 0) * 64 + lane) * 8];
                    s8v v1f = *(const s8v*)&VTs[p][((ob * 2 + 1) * 64 + lane) * 8];
                    O[ob] = __builtin_amdgcn_mfma_f32_16x16x32_bf16(v0f, pf0, O[ob], 0, 0, 0);
                    O[ob] = __builtin_amdgcn_mfma_f32_16x16x32_bf16(v1f, pf1, O[ob], 0, 0, 0);
                }
            }
            __syncthreads();   // buffer p consumed by all; prefetch into p^1 landed
        }

        // ---- epilogue: full denominator -> normalized bf16 output ----
        lr += __shfl_xor(lr, 16); lr += __shfl_xor(lr, 32);
        const float inv = 1.f / lr;
        const int qrow = q0 + w * 16 + l15;
        const size_t ybase = (size_t)qrow * DM + cq;
        #pragma unroll
        for (int ob = 0; ob < 4; ++ob) {
            unsigned short o[4];
            #pragma unroll
            for (int rg = 0; rg < 4; ++rg) o[rg] = f2bf(O[ob][rg] * inv);
            unsigned long long pk; memcpy(&pk, o, 8);
            *(unsigned long long*)&yout[ybase + ob * 16 + quad * 4] = pk;
        }
    }
}

// --------------- the cooperative mega-kernel: 4 stages ---------------
__global__ __launch_bounds__(512, 1)
void mega(const float* __restrict__ x, const float* __restrict__ Wqkv,
          const float* __restrict__ bqkv, const float* __restrict__ Wproj,
          const float* __restrict__ bproj, float* __restrict__ out,
          unsigned short* __restrict__ xb, unsigned short* __restrict__ wqkvb,
          unsigned short* __restrict__ wprjb, unsigned short* __restrict__ qbuf,
          unsigned short* __restrict__ kbuf, unsigned short* __restrict__ vTb,
          unsigned short* __restrict__ yattb) {
    cg::grid_group grid = cg::this_grid();
    __shared__ __align__(16) char smem[57344];   // union: gemm1 57.3K / attn 48K / gemm2 32K

    // ---- stage 1: fp32 -> bf16 (grid-stride) ----
    {
        const int n0 = T_SEQ * DM / 8, n1 = 3 * DM * DM / 8, n2 = DM * DM / 8;
        const int ntot = n0 + n1 + n2;
        for (int i = blockIdx.x * 512 + threadIdx.x; i < ntot; i += 256 * 512) {
            const float* in; unsigned short* o8; int j;
            if (i < n0)           { in = x;     o8 = xb;    j = i; }
            else if (i < n0 + n1) { in = Wqkv;  o8 = wqkvb; j = i - n0; }
            else                  { in = Wproj; o8 = wprjb; j = i - n0 - n1; }
            const float4* p = (const float4*)(in + (size_t)j * 8);
            float4 va = p[0], vb = p[1];
            unsigned short o[8] = {f2bf(va.x), f2bf(va.y), f2bf(va.z), f2bf(va.w),
                                   f2bf(vb.x), f2bf(vb.y), f2bf(vb.z), f2bf(vb.w)};
            uint4 pk; memcpy(&pk, o, 16);
            *(uint4*)(o8 + (size_t)j * 8) = pk;
        }
    }
    __threadfence();
    grid.sync();
    __threadfence();

    // ---- stage 2: qkv = x @ Wqkv^T + b (256x192, r7-proven) ----
    gemm_body<2, 256, 192, 2, 4>(smem, xb, wqkvb, bqkv, nullptr,
                                 qbuf, kbuf, vTb, T_SEQ, 3 * DM, DM, 16, 8, 4);
    __threadfence();
    grid.sync();
    __threadfence();

    // ---- stage 3: attention, no k-split, normalized output ----
    attn_body(smem, qbuf, kbuf, vTb, yattb);
    __threadfence();
    grid.sync();
    __threadfence();

    // ---- stage 4: out = yatt @ Wproj^T + b (128x128, 8 waves) ----
    gemm_body<0, 128, 128, 2, 4>(smem, yattb, wprjb, bproj, out,
                                 nullptr, nullptr, nullptr, T_SEQ, DM, DM, 8, 4, 8);
}

extern "C" void kernel_launch(void* const* d_in, const int* in_sizes, int n_in,
                              void* d_out, int out_size, void* d_ws, size_t ws_size,
                              hipStream_t stream) {
    const float* x     = (const float*)d_in[0];
    const float* Wqkv  = (const float*)d_in[1];
    const float* bqkv  = (const float*)d_in[2];
    const float* Wproj = (const float*)d_in[3];
    const float* bproj = (const float*)d_in[4];
    float* out = (float*)d_out;

    char* ws = (char*)d_ws;
    unsigned short* qbuf  = (unsigned short*)(ws);                    // @0   8 MB
    unsigned short* kbuf  = (unsigned short*)(ws + ( 8u << 20));      // @8   8 MB
    unsigned short* vTb   = (unsigned short*)(ws + (16u << 20));      // @16  8 MB (fragment image)
    unsigned short* yattb = (unsigned short*)(ws + (24u << 20));      // @24  8 MB
    unsigned short* wprjb = (unsigned short*)(ws + (32u << 20));      // @32  2 MB
    unsigned short* xb    = (unsigned short*)(ws + (35u << 20));      // @35  8 MB
    unsigned short* wqkvb = (unsigned short*)(ws + (43u << 20));      // @43  6 MB

    void* args[] = {
        (void*)&x, (void*)&Wqkv, (void*)&bqkv, (void*)&Wproj, (void*)&bproj,
        (void*)&out, (void*)&xb, (void*)&wqkvb, (void*)&wprjb,
        (void*)&qbuf, (void*)&kbuf, (void*)&vTb, (void*)&yattb
    };
    hipLaunchCooperativeKernel((void*)mega, dim3(256), dim3(512), args, 0, stream);
}

// Round 13
// 211.842 us; speedup vs baseline: 2.6854x; 2.6854x over previous
//
#include <hip/hip_runtime.h>
#include <math.h>
#include <string.h>

#define T_SEQ 4096
#define DM 1024
#define NH 16
#define HD 64

typedef short s8v __attribute__((ext_vector_type(8)));
typedef float f4v __attribute__((ext_vector_type(4)));

__device__ inline unsigned short f2bf(float f) {
    unsigned u; memcpy(&u, &f, 4);
    u = u + 0x7fffu + ((u >> 16) & 1u);   // RNE
    return (unsigned short)(u >> 16);
}

__device__ inline float bf2f(unsigned short s) {
    unsigned u = (unsigned)s << 16;
    float f; memcpy(&f, &u, 4);
    return f;
}

__device__ inline float exp2fn(float x) {
#if __has_builtin(__builtin_amdgcn_exp2f)
    return __builtin_amdgcn_exp2f(x);
#else
    return exp2f(x);
#endif
}

__device__ inline void gld_lds16(const void* g, void* l) {
    __builtin_amdgcn_global_load_lds(
        (const __attribute__((address_space(1))) void*)g,
        (__attribute__((address_space(3))) void*)l, 16, 0, 0);
}

// ------------- fp32 -> bf16, three tensors in one launch -------------
__global__ __launch_bounds__(256)
void cvt3(const float* __restrict__ i0, unsigned short* __restrict__ o0, int n0,
          const float* __restrict__ i1, unsigned short* __restrict__ o1, int n1,
          const float* __restrict__ i2, unsigned short* __restrict__ o2, int n2) {
    int i = blockIdx.x * 256 + threadIdx.x;
    const float* in; unsigned short* out; int j;
    if (i < n0)           { in = i0; out = o0; j = i; }
    else if (i < n0 + n1) { in = i1; out = o1; j = i - n0; }
    else if (i < n0 + n1 + n2) { in = i2; out = o2; j = i - n0 - n1; }
    else return;
    const float4* p = (const float4*)(in + (size_t)j * 8);
    float4 a = p[0], b = p[1];
    unsigned short o[8] = {f2bf(a.x), f2bf(a.y), f2bf(a.z), f2bf(a.w),
                           f2bf(b.x), f2bf(b.y), f2bf(b.z), f2bf(b.w)};
    uint4 pk; memcpy(&pk, o, 16);
    *(uint4*)(out + (size_t)j * 8) = pk;
}

// ------------- bf16 MFMA GEMM, FAT TILES:  C = A @ B^T + bias -------------
// (round-7-proven; rounds 2-9 and 12 showed per-GEMM time invariant to
// schedule, bytes, occupancy, fusion, and cooperative fusion -- final form.)
// MODE 2: qkv-special (Q/K row-major bf16, V sigma fragment-image).
// MODE 0: fp32 row-major out + bias.
template<int MODE, int TM, int TN, int WR, int WC>
__global__ __launch_bounds__(WR * WC * 64, 1)
void gemm_tile(const unsigned short* __restrict__ A, const unsigned short* __restrict__ B,
               const float* __restrict__ bias, void* __restrict__ Cout,
               unsigned short* __restrict__ qbuf, unsigned short* __restrict__ kbuf2,
               unsigned short* __restrict__ vT,
               int M, int N, int K, int nbx, int patchw, int patchh) {
    constexpr int W  = WR * WC;          // waves per block
    constexpr int MF = TM / WR / 16;     // A frags per wave
    constexpr int NF = TN / WC / 16;     // B frags per wave
    constexpr int NGA = TM / 16, NGB = TN / 16, NG = NGA + NGB;
    __shared__ __align__(16) short As[2][TM * 32];
    __shared__ __align__(16) short Bs[2][TN * 32];
    const int tid = threadIdx.x;
    const int w = tid >> 6, lane = tid & 63;
    const int wr = w / WC, wc = w % WC;
    const int l15 = lane & 15, quad = lane >> 4;

    // XCD-patch block swizzle (bijective: grid = 8 * patchw * patchh)
    const int bl = blockIdx.x;
    const int xcd = bl & 7, ii = bl >> 3;
    const int pxn = nbx / patchw;
    const int bx = (xcd % pxn) * patchw + ii % patchw;
    const int by = (xcd / pxn) * patchh + ii / patchw;
    const int m0 = by * TM, n0 = bx * TN;

    f4v acc[MF][NF];
    #pragma unroll
    for (int i = 0; i < MF; ++i)
        #pragma unroll
        for (int j = 0; j < NF; ++j) acc[i][j] = (f4v){0.f, 0.f, 0.f, 0.f};

    // stage: 16-row group g (A: 0..NGA-1, B: NGA..NG-1), 1 KB per group:
    // lane l -> row (g*16 + l&15), k-chunk (l>>4)*8; LDS linear lane*16B.
    auto stage = [&](int buf, int k0) {
        for (int g = w; g < NG; g += W) {
            const unsigned short* src;
            short* dst;
            if (g < NGA) {
                src = A + (size_t)(m0 + g * 16 + l15) * K + quad * 8 + k0;
                dst = &As[buf][g * 512];
            } else {
                src = B + (size_t)(n0 + (g - NGA) * 16 + l15) * K + quad * 8 + k0;
                dst = &Bs[buf][(g - NGA) * 512];
            }
            gld_lds16(src, dst);
        }
    };
    auto compute = [&](int buf) {
        s8v af[MF], bfr[NF];
        #pragma unroll
        for (int i = 0; i < MF; ++i)
            af[i] = *(const s8v*)&As[buf][((wr * MF + i) * 64 + lane) * 8];
        #pragma unroll
        for (int j = 0; j < NF; ++j)
            bfr[j] = *(const s8v*)&Bs[buf][((wc * NF + j) * 64 + lane) * 8];
        #pragma unroll
        for (int i = 0; i < MF; ++i)
            #pragma unroll
            for (int j = 0; j < NF; ++j)
                acc[i][j] = __builtin_amdgcn_mfma_f32_16x16x32_bf16(af[i], bfr[j], acc[i][j], 0, 0, 0);
    };

    stage(0, 0);
    __syncthreads();
    for (int k0 = 0; k0 < K; k0 += 64) {
        stage(1, k0 + 32);                 // in flight under compute(0)
        compute(0);
        __syncthreads();
        if (k0 + 64 < K) stage(0, k0 + 64);
        compute(1);
        __syncthreads();
    }

    float bj[NF];
    #pragma unroll
    for (int j = 0; j < NF; ++j) bj[j] = bias[n0 + wc * (TN / WC) + j * 16 + l15];

    if (MODE == 2) {
        #pragma unroll
        for (int j = 0; j < NF; ++j) {
            const int ccol = n0 + wc * (TN / WC) + j * 16;   // wave-uniform, 16-aligned
            if (ccol >= 2 * DM) {
                // V -> sigma fragment-image. head hh, d = (ccol&63) + l15,
                // key = tile*64 + it*16 + quad*4 + rg, it = i&3,
                // tile = (m0 + wr*(TM/WR))/64 + (i>>2)
                const int hh = (ccol - 2 * DM) >> 6;
                const int ob = (ccol & 63) >> 4;
                #pragma unroll
                for (int i = 0; i < MF; ++i) {
                    const int tile = (m0 + wr * (TM / WR)) / 64 + (i >> 2);
                    const int it = i & 3;
                    unsigned short o[4];
                    #pragma unroll
                    for (int rg = 0; rg < 4; ++rg) o[rg] = f2bf(acc[i][j][rg] + bj[j]);
                    unsigned long long pk; memcpy(&pk, o, 8);
                    size_t off = (size_t)hh * 262144 + (size_t)tile * 4096
                               + (size_t)((ob * 2 + (it >> 1)) * 64 + lane) * 8 + (it & 1) * 4;
                    *(unsigned long long*)&vT[off] = pk;
                }
            } else {
                unsigned short* dst = (ccol < DM) ? qbuf : kbuf2;
                const int col = (ccol < DM) ? (ccol + l15) : (ccol - DM + l15);
                #pragma unroll
                for (int i = 0; i < MF; ++i) {
                    #pragma unroll
                    for (int rg = 0; rg < 4; ++rg) {
                        int row = m0 + wr * (TM / WR) + i * 16 + quad * 4 + rg;
                        dst[(size_t)row * DM + col] = f2bf(acc[i][j][rg] + bj[j]);
                    }
                }
            }
        }
    } else {
        #pragma unroll
        for (int i = 0; i < MF; ++i) {
            #pragma unroll
            for (int rg = 0; rg < 4; ++rg) {
                int row = m0 + wr * (TM / WR) + i * 16 + quad * 4 + rg;
                #pragma unroll
                for (int j = 0; j < NF; ++j) {
                    int col = n0 + wc * (TN / WC) + j * 16 + l15;
                    ((float*)Cout)[(size_t)row * N + col] = acc[i][j][rg] + bj[j];
                }
            }
        }
    }
}

// ---- static-max softmax step -> P fragments DIRECT IN REGISTERS ----
__device__ __forceinline__ void soft_step(f4v* st, bool diag, int qloc, int quad,
                                          float& lr, s8v& pf0, s8v& pf1) {
    const float C2  = 0.1803368851f;          // 0.125 * log2(e)
    const float MC2 = 12.0f * 0.1803368851f;  // fixed shift M=12
    float sv[4][4];
    #pragma unroll
    for (int kb = 0; kb < 4; ++kb)
        #pragma unroll
        for (int rg = 0; rg < 4; ++rg) {
            float s = st[kb][rg];
            if (diag && (kb * 16 + quad * 4 + rg > qloc)) s = -3.0e38f;
            float t = exp2fn(fmaf(s, C2, -MC2));
            sv[kb][rg] = t;
            lr += t;
        }
    int pk[4][2];
    #pragma unroll
    for (int kb = 0; kb < 4; ++kb) {
        unsigned u0 = __float_as_uint(sv[kb][0]) + 0x8000u;
        unsigned u1 = __float_as_uint(sv[kb][1]) + 0x8000u;
        unsigned u2 = __float_as_uint(sv[kb][2]) + 0x8000u;
        unsigned u3 = __float_as_uint(sv[kb][3]) + 0x8000u;
        pk[kb][0] = (int)__builtin_amdgcn_perm(u1, u0, 0x07060302);  // bf16(sv0)|bf16(sv1)<<16
        pk[kb][1] = (int)__builtin_amdgcn_perm(u3, u2, 0x07060302);
    }
    int4 a = {pk[0][0], pk[0][1], pk[1][0], pk[1][1]};
    int4 b = {pk[2][0], pk[2][1], pk[3][0], pk[3][1]};
    memcpy(&pf0, &a, 16);
    memcpy(&pf1, &b, 16);
}

// ---- MFMA flash attention: 512-thr blocks, 2-way k-split, paired phases ----
// (round-11 form, session-best total. Round-12's cooperative no-split variant
// regressed 2.3x: 1 block/CU removed the cross-block TLP hiding the per-tile
// stage->barrier chain. Do not fuse; do not drop the k-split.)
// Block map b = par*256 + a*16 + h keeps b%8 = h%8: all blocks of head h on
// one XCD, ~2 MB K/V working set per XCD (round-1's hard-won invariant).
// Per-wave causal logic:
//   lo waves (w<4, rows 0..63):  diag at kt==2qt,   skip kt==2qt+1
//   hi waves (w>=4, rows 64..127): diag at kt==2qt+1, never skip
//   qloc = (w&3)*16 + l15.
__global__ __launch_bounds__(512, 4)
void attn_mfma2p(const unsigned short* __restrict__ qb,
                 const unsigned short* __restrict__ kbf,
                 const unsigned short* __restrict__ vT,
                 unsigned short* __restrict__ y0,
                 unsigned short* __restrict__ y1,
                 float* __restrict__ lsum) {
    const int b = blockIdx.x;
    const int par = b >> 8;             // high bit: b%8 = h%8 preserved
    const int idx = b & 255;
    const int h = idx & 15, a = idx >> 4;
    const int tid = threadIdx.x;
    const int w = tid >> 6, lane = tid & 63;
    const int quad = lane >> 4, l15 = lane & 15;
    const int cq = h * HD;
    unsigned short* ypar = par ? y1 : y0;
    float* lpar = lsum + ((size_t)par * NH + h) * T_SEQ;
    const unsigned short* vbase = vT + (size_t)h * 262144;   // per-head V image

    __shared__ short KB[2][4096];
    __shared__ short VTs[2][4096];
    __shared__ short QB[8192];

    const bool lo = (w < 4);
    const int qloc = (w & 3) * 16 + l15;

    for (int ph = 0; ph < 2; ++ph) {
        const int qt = ph ? (31 - a) : a;
        const int q0 = qt * 128;
        const int nk = qt + 1;              // tiles kt = par, par+2, ..., par+2qt
        const int kt0 = par * 64;

        __syncthreads();   // previous phase LDS fully consumed
        // ---- stage Q (128 rows x 64 d = 16 KB; 1024 chunks, 2 rounds) ----
        #pragma unroll
        for (int rr = 0; rr < 2; ++rr) {
            int ch = rr * 512 + tid;
            int qg = ch >> 7, hf = (ch >> 6) & 1, ln = ch & 63;
            gld_lds16(qb + (size_t)(q0 + qg * 16 + (ln & 15)) * DM + cq + hf * 32 + ((ln >> 4) << 3),
                      &QB[(ch & ~63) * 8]);
        }
        // ---- stage first K/V tile (8 KB each = 512 chunks, 1 round) ----
        {
            int ch = tid;
            int blk = ch >> 7, hf = (ch >> 6) & 1, ln = ch & 63;
            gld_lds16(kbf + (size_t)(kt0 + blk * 16 + (ln & 15)) * DM + cq + hf * 32 + ((ln >> 4) << 3),
                      &KB[0][(ch & ~63) * 8]);
            gld_lds16(vbase + (size_t)(kt0 >> 6) * 4096 + (size_t)ch * 8,
                      &VTs[0][(ch & ~63) * 8]);
        }
        __syncthreads();

        s8v qf[2];
        #pragma unroll
        for (int hf = 0; hf < 2; ++hf)
            qf[hf] = *(const s8v*)&QB[(((w * 2 + hf) * 64) + lane) * 8];

        f4v O[4];
        #pragma unroll
        for (int ob = 0; ob < 4; ++ob) O[ob] = (f4v){0.f, 0.f, 0.f, 0.f};
        float lr = 0.f;

        for (int i = 0; i < nk; ++i) {
            const int kt = par + 2 * i;
            const int p = i & 1;
            const bool diag = lo ? (kt == 2 * qt) : (kt == 2 * qt + 1);
            const bool skip = lo && (kt == 2 * qt + 1);
            if (i < nk - 1) {                      // prefetch next tile (stride 128 keys)
                const int k1 = kt0 + (i + 1) * 128;
                int ch = tid;
                int blk = ch >> 7, hf = (ch >> 6) & 1, ln = ch & 63;
                gld_lds16(kbf + (size_t)(k1 + blk * 16 + (ln & 15)) * DM + cq
                              + hf * 32 + ((ln >> 4) << 3),
                          &KB[p ^ 1][(ch & ~63) * 8]);
                gld_lds16(vbase + (size_t)(k1 >> 6) * 4096 + (size_t)ch * 8,
                          &VTs[p ^ 1][(ch & ~63) * 8]);
            }

            if (!skip) {
                // ---- S^T for this wave's 16 q-rows ----
                f4v st[4];
                #pragma unroll
                for (int kb = 0; kb < 4; ++kb) {
                    s8v k0f = *(const s8v*)&KB[p][((kb * 2 + 0) * 64 + lane) * 8];
                    s8v k1f = *(const s8v*)&KB[p][((kb * 2 + 1) * 64 + lane) * 8];
                    f4v c = (f4v){0.f, 0.f, 0.f, 0.f};
                    c = __builtin_amdgcn_mfma_f32_16x16x32_bf16(k0f, qf[0], c, 0, 0, 0);
                    c = __builtin_amdgcn_mfma_f32_16x16x32_bf16(k1f, qf[1], c, 0, 0, 0);
                    st[kb] = c;
                }
                // ---- softmax + P fragments in registers ----
                s8v pf0, pf1;
                soft_step(st, diag, qloc, quad, lr, pf0, pf1);
                // ---- O^T += V^T P^T ----
                #pragma unroll
                for (int ob = 0; ob < 4; ++ob) {
                    s8v v0f = *(const s8v*)&VTs[p][((ob * 2 + 0) * 64 + lane) * 8];
                    s8v v1f = *(const s8v*)&VTs[p][((ob * 2 + 1) * 64 + lane) * 8];
                    O[ob] = __builtin_amdgcn_mfma_f32_16x16x32_bf16(v0f, pf0, O[ob], 0, 0, 0);
                    O[ob] = __builtin_amdgcn_mfma_f32_16x16x32_bf16(v1f, pf1, O[ob], 0, 0, 0);
                }
            }
            __syncthreads();   // buffer p consumed by all; prefetch into p^1 landed
        }

        // ---- epilogue: unnormalized partial O (bf16) + partial l (fp32) ----
        lr += __shfl_xor(lr, 16); lr += __shfl_xor(lr, 32);
        const int qrow = q0 + w * 16 + l15;
        const size_t ybase = (size_t)qrow * DM + cq;
        #pragma unroll
        for (int ob = 0; ob < 4; ++ob) {
            unsigned short o[4];
            #pragma unroll
            for (int rg = 0; rg < 4; ++rg) o[rg] = f2bf(O[ob][rg]);
            unsigned long long pk; memcpy(&pk, o, 8);
            *(unsigned long long*)&ypar[ybase + ob * 16 + quad * 4] = pk;
        }
        if (quad == 0) lpar[qrow] = lr;
    }
}

// ---- combine partials: y = (O0 + O1) / (l0 + l1), bf16 out ----
__global__ __launch_bounds__(256)
void attn_combine2(const unsigned short* __restrict__ y0,
                   const unsigned short* __restrict__ y1,
                   const float* __restrict__ lsum,
                   unsigned short* __restrict__ yout) {
    int i = blockIdx.x * 256 + threadIdx.x;
    int t = i >> 7, d8 = i & 127;
    int h = d8 >> 3;
    float l = lsum[(size_t)h * T_SEQ + t]
            + lsum[((size_t)NH + h) * T_SEQ + t];
    float inv = 1.f / l;
    size_t off = (size_t)t * DM + d8 * 8;
    uint4 ua = *(const uint4*)(y0 + off);
    uint4 ub = *(const uint4*)(y1 + off);
    const unsigned short* pa = (const unsigned short*)&ua;
    const unsigned short* pb = (const unsigned short*)&ub;
    unsigned short o[8];
    #pragma unroll
    for (int k = 0; k < 8; ++k)
        o[k] = f2bf((bf2f(pa[k]) + bf2f(pb[k])) * inv);
    uint4 pk; memcpy(&pk, o, 16);
    *(uint4*)(yout + off) = pk;
}

extern "C" void kernel_launch(void* const* d_in, const int* in_sizes, int n_in,
                              void* d_out, int out_size, void* d_ws, size_t ws_size,
                              hipStream_t stream) {
    const float* x     = (const float*)d_in[0];
    const float* Wqkv  = (const float*)d_in[1];
    const float* bqkv  = (const float*)d_in[2];
    const float* Wproj = (const float*)d_in[3];
    const float* bproj = (const float*)d_in[4];
    float* out = (float*)d_out;

    char* ws = (char*)d_ws;
    unsigned short* qbuf  = (unsigned short*)(ws);                    // @0   8 MB
    unsigned short* kbuf  = (unsigned short*)(ws + ( 8u << 20));      // @8   8 MB
    unsigned short* vTb   = (unsigned short*)(ws + (16u << 20));      // @16  8 MB (fragment image)
    unsigned short* yattb = (unsigned short*)(ws + (24u << 20));      // @24  8 MB
    unsigned short* wprjb = (unsigned short*)(ws + (32u << 20));      // @32  2 MB
    float*          lsum  = (float*)         (ws + (34u << 20));      // @34  0.5 MB (2 partials)
    unsigned short* xb    = (unsigned short*)(ws + (35u << 20));      // @35  8 MB (dead after gemm1)
    unsigned short* wqkvb = (unsigned short*)(ws + (43u << 20));      // @43  6 MB (dead after gemm1)
    unsigned short* y0p   = (unsigned short*)(ws + (35u << 20));      // @35  8 MB (over xb)
    unsigned short* y1p   = (unsigned short*)(ws + (43u << 20));      // @43  8 MB (over wqkvb)

    {
        int n0 = T_SEQ * DM / 8, n1 = 3 * DM * DM / 8, n2 = DM * DM / 8;
        cvt3<<<dim3((n0 + n1 + n2 + 255) / 256), dim3(256), 0, stream>>>(
            x, xb, n0, Wqkv, wqkvb, n1, Wproj, wprjb, n2);
    }
    // qkv = x @ Wqkv^T + b : 256x192 tile, grid 16x16 = 256 = 1 block/CU,
    // 512 threads (8 waves 2x4); XCD patch 8 bx x 4 by (pxn=2)
    gemm_tile<2, 256, 192, 2, 4><<<dim3(256), dim3(512), 0, stream>>>(
        xb, wqkvb, bqkv, nullptr, qbuf, kbuf, vTb, T_SEQ, 3 * DM, DM, 16, 8, 4);
    // attention: 512-thr blocks, 2-way k-split, grid 512 = 2 blocks/CU
    attn_mfma2p<<<dim3(512), dim3(512), 0, stream>>>(qbuf, kbuf, vTb, y0p, y1p, lsum);
    attn_combine2<<<dim3(T_SEQ * DM / 8 / 256), dim3(256), 0, stream>>>(y0p, y1p, lsum, yattb);
    // out = yatt @ Wproj^T + b : 128x128 tile, grid 8x32 = 256 = 1 block/CU
    gemm_tile<0, 128, 128, 2, 2><<<dim3(256), dim3(256), 0, stream>>>(
        yattb, wprjb, bproj, out, nullptr, nullptr, nullptr, T_SEQ, DM, DM, 8, 4, 8);
}